// Round 16
// baseline (40.383 us; speedup 1.0000x reference)
//
#include <hip/hip_runtime.h>
#include <math.h>

#define TWO_PI_F 6.28318530717958647692f

typedef unsigned int u32;
typedef __attribute__((ext_vector_type(4))) float    f4;
typedef __attribute__((ext_vector_type(16))) float   f16v;
typedef __attribute__((ext_vector_type(2))) float    f2;
typedef __attribute__((ext_vector_type(2))) _Float16 h2;
typedef __attribute__((ext_vector_type(4))) _Float16 h4;
typedef __attribute__((ext_vector_type(8))) _Float16 h8;

union B8 { h8 v; h4 q[2]; };
union C2 { u32 w[2]; h4 v; };
union P4 { h2 a[4]; h8 v; };

#if __has_builtin(__builtin_amdgcn_cvt_pkrtz)
__device__ __forceinline__ h2 CVTPK(float a, float b) {
    return __builtin_bit_cast(h2, __builtin_amdgcn_cvt_pkrtz(a, b));
}
#else
__device__ __forceinline__ h2 CVTPK(float a, float b) {
    return (h2){(_Float16)a, (_Float16)b};
}
#endif

// ---------------------------------------------------------------------------
// MFMA formulation (r14/r15 geometry) with relu-split epilogue:
//   relu(x) = (x+|x|)/2  =>  0.5*sum_h w2*relu(p) =
//       [one extra MFMA: A-row = L = 0.25*V^T w2, every C reg = lin]   (linear)
//     + [sum_e v_fma_f32(|c_e|, 0.25*w2_e, acc): abs is a FREE src mod] (abs)
// Per iter: 6 MFMAs + 64 abs-fma, no fmax / no cvt / no fdot2.
// 2080 upper-triangular 32x32 blocks, 256 threads; o = wv>>1 wave-invariant.
// ---------------------------------------------------------------------------
__global__ __launch_bounds__(256) void gd_mfma(
    const float* __restrict__ z,  const float* __restrict__ s,
    const float* __restrict__ W1, const float* __restrict__ b1,
    const float* __restrict__ W2, const float* __restrict__ b2v,
    float* __restrict__ out, int N, int NB)
{
    __shared__ __attribute__((aligned(16))) _Float16 Ald[64][24]; // 3KB
    __shared__ __attribute__((aligned(16))) h4 peb[64];           // 512B
    __shared__ __attribute__((aligned(16))) h2 P2[1024];          // 4KB {ct,st}
    __shared__ __attribute__((aligned(16))) float S[2][32][36];   // 9.2KB
    __shared__ __attribute__((aligned(16))) float w2f[64];        // 256B
    __shared__ __attribute__((aligned(16))) _Float16 Lld[16];     // 32B
    __shared__ f2 strig[64];                                      // 512B

    // --- triangular block decode: u -> (bi, bj), bj >= bi ---
    int u = blockIdx.x;
    int M = 2 * NB + 1;
    float disc = (float)(M * M - 8 * u);
    int bi = (int)(((float)M - sqrtf(disc)) * 0.5f);
    if (bi < 0) bi = 0;
    if (bi > NB - 1) bi = NB - 1;
    while (bi > 0 && bi * (M - bi) / 2 > u) --bi;
    while ((bi + 1) * (M - (bi + 1)) / 2 <= u) ++bi;
    int bj = bi + (u - bi * (M - bi) / 2);

    int t    = threadIdx.x;
    int lane = t & 63;

    if (t < 64) {                        // trig + pe + V^T rows + w2f
        int grow = (t < 32) ? (bi * 32 + t) : (bj * 32 + (t - 32));
        float ang = TWO_PI_F * s[grow];
        float c1 = __cosf(ang), s1 = __sinf(ang);
        float c2 = c1 * c1 - s1 * s1, s2 = 2.0f * c1 * s1;
        strig[t] = (f2){c1, s1};
        peb[t]   = (h4){(_Float16)c1, (_Float16)s1, (_Float16)c2, (_Float16)s2};
        w2f[t]   = W2[t];

        float zc = b1[t];
#pragma unroll
        for (int zz = 0; zz < 32; ++zz)
            zc = fmaf(z[zz], W1[(10 + zz) * 64 + t], zc);

        h8 row0, row1;
#pragma unroll
        for (int k = 0; k < 8; ++k) row0[k] = (_Float16)W1[k * 64 + t];
        row1 = (h8)0;
        row1[0] = (_Float16)W1[8 * 64 + t];   // wc
        row1[1] = (_Float16)W1[9 * 64 + t];   // ws
        row1[2] = (_Float16)zc;               // bias via "1" feature
        *(h8*)&Ald[t][0] = row0;
        *(h8*)&Ald[t][8] = row1;
    }
    __syncthreads();

    // --- P2 build (all threads) + L build (t<16) ---
    {
        int base = t * 4;
        int il = base >> 5, j0 = base & 31;
        f2 ci = strig[il];
        P4 pk;
#pragma unroll
        for (int c = 0; c < 4; ++c) {
            f2 cj = strig[32 + j0 + c];
            float ctv = fmaf(ci.x, cj.x, ci.y * cj.y);
            float stv = fabsf(fmaf(ci.y, cj.x, -(ci.x * cj.y)));
            pk.a[c] = CVTPK(ctv, stv);
        }
        *(h8*)&P2[base] = pk.v;
    }
    if (t < 16) {                        // L[k] = 0.25 * sum_h V[k,h]*w2[h]
        float acc = 0.0f;
        for (int h = 0; h < 64; ++h)
            acc = fmaf((float)Ald[h][t], w2f[h], acc);
        Lld[t] = (_Float16)(0.25f * acc);
    }

    int n = lane & 31;
    int q = lane >> 5;

    // A-frags + 0.25*w2 registers matched to C row layout
    h8 afr[2];
    float w2v[2][16];
#pragma unroll
    for (int H = 0; H < 2; ++H) {
        afr[H] = *(const h8*)&Ald[H * 32 + n][q * 8];
#pragma unroll
        for (int e = 0; e < 16; ++e)
            w2v[H][e] = 0.25f * w2f[(e & 3) + 8 * (e >> 2) + 4 * q + 32 * H];
    }
    __syncthreads();

    h8 afrL = *(const h8*)&Lld[q * 8];   // L replicated across all A rows

    // --- phase 2: dual-stream MFMA loop, abs-fma epilogue ---
    int wv   = t >> 6;
    int o    = wv >> 1;          // orientation: wave-invariant
    int base = (wv & 1) * 16;    // il base

    h4 pe_inv = peb[32 + n];     // fixed-role pe row (iteration-invariant)

#pragma unroll
    for (int i = 0; i < 8; ++i) {
        int ilA = base + i;
        int ilB = base + i + 8;

        h4 varA = peb[ilA];                        // broadcast (uniform addr)
        h4 varB = peb[ilB];
        u32 pwA = *(const u32*)&P2[ilA * 32 + n];  // conflict-free b32
        u32 pwB = *(const u32*)&P2[ilB * 32 + n];

        B8 bA, bB;
        {
            h4 pa = o ? pe_inv : varA;
            h4 pb = o ? varA : pe_inv;
            C2 cc; cc.w[0] = pwA; cc.w[1] = 0x00003C00u;   // {ct,st,1,0}
            bA.q[0] = q ? cc.v : pa;
            bA.q[1] = q ? (h4)0 : pb;
        }
        {
            h4 pa = o ? pe_inv : varB;
            h4 pb = o ? varB : pe_inv;
            C2 cc; cc.w[0] = pwB; cc.w[1] = 0x00003C00u;
            bB.q[0] = q ? cc.v : pa;
            bB.q[1] = q ? (h4)0 : pb;
        }

        f16v a0A = __builtin_amdgcn_mfma_f32_32x32x16_f16(afr[0], bA.v, (f16v)(0.0f), 0, 0, 0);
        f16v a1A = __builtin_amdgcn_mfma_f32_32x32x16_f16(afr[1], bA.v, (f16v)(0.0f), 0, 0, 0);
        f16v lnA = __builtin_amdgcn_mfma_f32_32x32x16_f16(afrL,   bA.v, (f16v)(0.0f), 0, 0, 0);
        f16v a0B = __builtin_amdgcn_mfma_f32_32x32x16_f16(afr[0], bB.v, (f16v)(0.0f), 0, 0, 0);
        f16v a1B = __builtin_amdgcn_mfma_f32_32x32x16_f16(afr[1], bB.v, (f16v)(0.0f), 0, 0, 0);
        f16v lnB = __builtin_amdgcn_mfma_f32_32x32x16_f16(afrL,   bB.v, (f16v)(0.0f), 0, 0, 0);

        float cA0 = 0.f, cA1 = 0.f, cA2 = 0.f, cA3 = 0.f;
        float cB0 = 0.f, cB1 = 0.f, cB2 = 0.f, cB3 = 0.f;
#pragma unroll
        for (int e = 0; e < 8; ++e) {      // abs is a free src modifier
            cA0 = fmaf(fabsf(a0A[e]),     w2v[0][e],     cA0);
            cA1 = fmaf(fabsf(a0A[e + 8]), w2v[0][e + 8], cA1);
            cA2 = fmaf(fabsf(a1A[e]),     w2v[1][e],     cA2);
            cA3 = fmaf(fabsf(a1A[e + 8]), w2v[1][e + 8], cA3);
            cB0 = fmaf(fabsf(a0B[e]),     w2v[0][e],     cB0);
            cB1 = fmaf(fabsf(a0B[e + 8]), w2v[0][e + 8], cB1);
            cB2 = fmaf(fabsf(a1B[e]),     w2v[1][e],     cB2);
            cB3 = fmaf(fabsf(a1B[e + 8]), w2v[1][e + 8], cB3);
        }
        float psA = (cA0 + cA1) + (cA2 + cA3);
        float psB = (cB0 + cB1) + (cB2 + cB3);
        psA += __shfl_xor(psA, 32);        // abs part: sum the two K-halves
        psB += __shfl_xor(psB, 32);
        psA += lnA[0];                     // linear part (all C rows equal)
        psB += lnB[0];
        if (q == 0) {
            S[o][ilA][n] = psA;
            S[o][ilB][n] = psB;
        }
    }
    __syncthreads();

    // --- phase 3: symmetrized output + mirror (coalesced f4 stores) ---
    float b2 = b2v[0];
    {
        int il = t >> 3;
        int j0 = (t & 7) * 4;
        f4 a = *(const f4*)&S[0][il][j0];
        f4 b = *(const f4*)&S[1][il][j0];
        f4 v;
#pragma unroll
        for (int c = 0; c < 4; ++c) {
            float x = a[c] + b[c] + b2;
            if (bi == bj && il == j0 + c) x = -1e9f;
            v[c] = x;
        }
        *(f4*)&out[(size_t)(bi * 32 + il) * N + bj * 32 + j0] = v;

        if (bj > bi) {
            int jl = t >> 3;
            int i0 = (t & 7) * 4;
            f4 m;
#pragma unroll
            for (int c = 0; c < 4; ++c)
                m[c] = S[0][i0 + c][jl] + S[1][i0 + c][jl] + b2;
            *(f4*)&out[(size_t)(bj * 32 + jl) * N + bi * 32 + i0] = m;
        }
    }
}

extern "C" void kernel_launch(void* const* d_in, const int* in_sizes, int n_in,
                              void* d_out, int out_size, void* d_ws, size_t ws_size,
                              hipStream_t stream) {
    const float* z  = (const float*)d_in[0];  // [32]
    const float* s  = (const float*)d_in[1];  // [N]
    const float* W1 = (const float*)d_in[2];  // [42,64]
    const float* b1 = (const float*)d_in[3];  // [64]
    const float* W2 = (const float*)d_in[4];  // [64]
    const float* b2 = (const float*)d_in[5];  // [1]
    int N = in_sizes[1];                      // 2048

    float* out = (float*)d_out;
    int NB = N / 32;
    int nblk = NB * (NB + 1) / 2;             // 2080 for N=2048
    gd_mfma<<<nblk, 256, 0, stream>>>(z, s, W1, b1, W2, b2, out, N, NB);
}

// Round 17
// 27.057 us; speedup vs baseline: 1.4925x; 1.4925x over previous
//
#include <hip/hip_runtime.h>
#include <math.h>

#define TWO_PI_F 6.28318530717958647692f

typedef unsigned int u32;
typedef __attribute__((ext_vector_type(4))) float    f4;
typedef __attribute__((ext_vector_type(16))) float   f16v;
typedef __attribute__((ext_vector_type(2))) float    f2;
typedef __attribute__((ext_vector_type(2))) _Float16 h2;
typedef __attribute__((ext_vector_type(4))) _Float16 h4;
typedef __attribute__((ext_vector_type(8))) _Float16 h8;

union B8 { h8 v; h4 q[2]; };
union C2 { u32 w[2]; h4 v; };
union P4 { h2 a[4]; h8 v; };

#if __has_builtin(__builtin_amdgcn_cvt_pkrtz)
__device__ __forceinline__ h2 CVTPK(float a, float b) {
    return __builtin_bit_cast(h2, __builtin_amdgcn_cvt_pkrtz(a, b));
}
#else
__device__ __forceinline__ h2 CVTPK(float a, float b) {
    return (h2){(_Float16)a, (_Float16)b};
}
#endif

// ---------------------------------------------------------------------------
// r15 geometry + relu-split epilogue (unbundled from r16's regressions):
//   0.5*sum_h w2*relu(p) = 0.25*sum w2*p  +  0.25*sum w2*|p|
//   abs term: v_fma_f32 with FREE |src| modifier, 1 op per h-value
//   linear term: separable lin(v) = LA[roleA] + LB[roleB] + ct*Lp8 + st*Lp9
//     Lp[k] = 0.25*sum_h V[k,h]w2[h] via 64-lane butterfly (no serial chain)
//     LA/LB per row: 4-5 fma in setup. NO third MFMA, NO extra C-frags.
// 2080 upper-triangular 32x32 blocks, 256 threads, 4 MFMAs/iter dual-stream.
// ---------------------------------------------------------------------------
__global__ __launch_bounds__(256, 3) void gd_mfma(
    const float* __restrict__ z,  const float* __restrict__ s,
    const float* __restrict__ W1, const float* __restrict__ b1,
    const float* __restrict__ W2, const float* __restrict__ b2v,
    float* __restrict__ out, int N, int NB)
{
    __shared__ __attribute__((aligned(16))) _Float16 Ald[64][24]; // 3KB
    __shared__ __attribute__((aligned(16))) h4 peb[64];           // 512B
    __shared__ __attribute__((aligned(16))) h2 P2[1024];          // 4KB {ct,st}
    __shared__ __attribute__((aligned(16))) float S[2][32][36];   // 9.2KB
    __shared__ __attribute__((aligned(16))) f4 strig2[64];        // 1KB {c1,s1,c2,s2}
    __shared__ __attribute__((aligned(16))) float w2f[64];        // 256B
    __shared__ float Lp[12];                                      // 48B
    __shared__ float LA[64], LB[64];                              // 512B

    // --- triangular block decode: u -> (bi, bj), bj >= bi ---
    int u = blockIdx.x;
    int M = 2 * NB + 1;
    float disc = (float)(M * M - 8 * u);
    int bi = (int)(((float)M - sqrtf(disc)) * 0.5f);
    if (bi < 0) bi = 0;
    if (bi > NB - 1) bi = NB - 1;
    while (bi > 0 && bi * (M - bi) / 2 > u) --bi;
    while ((bi + 1) * (M - (bi + 1)) / 2 <= u) ++bi;
    int bj = bi + (u - bi * (M - bi) / 2);

    int t    = threadIdx.x;
    int lane = t & 63;

    if (t < 64) {                        // wave 0: trig + pe + V^T rows + Lp
        int grow = (t < 32) ? (bi * 32 + t) : (bj * 32 + (t - 32));
        float ang = TWO_PI_F * s[grow];
        float c1 = __cosf(ang), s1 = __sinf(ang);
        float c2 = c1 * c1 - s1 * s1, s2 = 2.0f * c1 * s1;
        strig2[t] = (f4){c1, s1, c2, s2};
        peb[t]    = (h4){(_Float16)c1, (_Float16)s1, (_Float16)c2, (_Float16)s2};
        float w2t = W2[t];
        w2f[t] = w2t;

        float zc = b1[t];
#pragma unroll
        for (int zz = 0; zz < 32; ++zz)
            zc = fmaf(z[zz], W1[(10 + zz) * 64 + t], zc);

        h8 row0, row1;
#pragma unroll
        for (int k = 0; k < 8; ++k) row0[k] = (_Float16)W1[k * 64 + t];
        row1 = (h8)0;
        row1[0] = (_Float16)W1[8 * 64 + t];   // wc
        row1[1] = (_Float16)W1[9 * 64 + t];   // ws
        row1[2] = (_Float16)zc;               // bias via "1" feature
        *(h8*)&Ald[t][0] = row0;
        *(h8*)&Ald[t][8] = row1;

        // Lp[k] = 0.25 * sum_h V[k,h]*w2[h] : 64-lane butterfly (wave 0)
        float q25 = 0.25f * w2t;
        float lv[11];
#pragma unroll
        for (int k = 0; k < 8; ++k) lv[k] = (float)row0[k] * q25;
        lv[8]  = (float)row1[0] * q25;
        lv[9]  = (float)row1[1] * q25;
        lv[10] = zc * q25;
#pragma unroll
        for (int off = 32; off; off >>= 1)
#pragma unroll
            for (int k = 0; k < 11; ++k)
                lv[k] += __shfl_xor(lv[k], off);
        if (t == 0) {
#pragma unroll
            for (int k = 0; k < 11; ++k) Lp[k] = lv[k];
        }
    }
    __syncthreads();

    // --- P2 build (all threads) + LA/LB rows (t<64) ---
    {
        int base = t * 4;
        int il = base >> 5, j0 = base & 31;
        f4 ci = strig2[il];
        P4 pk;
#pragma unroll
        for (int c = 0; c < 4; ++c) {
            f4 cj = strig2[32 + j0 + c];
            float ctv = fmaf(ci.x, cj.x, ci.y * cj.y);
            float stv = fabsf(fmaf(ci.y, cj.x, -(ci.x * cj.y)));
            pk.a[c] = CVTPK(ctv, stv);
        }
        *(h8*)&P2[base] = pk.v;
    }
    if (t < 64) {
        f4 tg = strig2[t];
        LA[t] = fmaf(Lp[0], tg.x, fmaf(Lp[1], tg.y,
                 fmaf(Lp[2], tg.z, fmaf(Lp[3], tg.w, Lp[10]))));
        LB[t] = fmaf(Lp[4], tg.x, fmaf(Lp[5], tg.y,
                 fmaf(Lp[6], tg.z, Lp[7] * tg.w)));
    }

    int n = lane & 31;
    int q = lane >> 5;

    // A-frags + 0.25*w2 f32 registers matched to C row layout
    h8 afr[2];
    float w2v[2][16];
#pragma unroll
    for (int H = 0; H < 2; ++H) {
        afr[H] = *(const h8*)&Ald[H * 32 + n][q * 8];
#pragma unroll
        for (int e = 0; e < 16; ++e)
            w2v[H][e] = 0.25f * w2f[(e & 3) + 8 * (e >> 2) + 4 * q + 32 * H];
    }
    __syncthreads();

    // --- phase 2: dual-stream MFMA loop, abs-fma epilogue + separable lin ---
    int wv   = t >> 6;
    int o    = wv >> 1;          // orientation: wave-invariant
    int base = (wv & 1) * 16;    // il base

    h4 pe_inv = peb[32 + n];     // fixed-role pe row (iteration-invariant)
    float laneInv = o ? LA[32 + n] : LB[32 + n];
    float Lp8r = Lp[8], Lp9r = Lp[9];

#pragma unroll
    for (int i = 0; i < 8; ++i) {
        int ilA = base + i;
        int ilB = base + i + 8;

        h4 varA = peb[ilA];                        // broadcast (uniform addr)
        h4 varB = peb[ilB];
        u32 pwA = *(const u32*)&P2[ilA * 32 + n];  // conflict-free b32
        u32 pwB = *(const u32*)&P2[ilB * 32 + n];
        float rowA = o ? LB[ilA] : LA[ilA];        // uniform broadcast reads
        float rowB = o ? LB[ilB] : LA[ilB];

        B8 bA, bB;
        {
            h4 pa = o ? pe_inv : varA;
            h4 pb = o ? varA : pe_inv;
            C2 cc; cc.w[0] = pwA; cc.w[1] = 0x00003C00u;   // {ct,st,1,0}
            bA.q[0] = q ? cc.v : pa;
            bA.q[1] = q ? (h4)0 : pb;
        }
        {
            h4 pa = o ? pe_inv : varB;
            h4 pb = o ? varB : pe_inv;
            C2 cc; cc.w[0] = pwB; cc.w[1] = 0x00003C00u;
            bB.q[0] = q ? cc.v : pa;
            bB.q[1] = q ? (h4)0 : pb;
        }

        f16v a0A = __builtin_amdgcn_mfma_f32_32x32x16_f16(afr[0], bA.v, (f16v)(0.0f), 0, 0, 0);
        f16v a1A = __builtin_amdgcn_mfma_f32_32x32x16_f16(afr[1], bA.v, (f16v)(0.0f), 0, 0, 0);
        f16v a0B = __builtin_amdgcn_mfma_f32_32x32x16_f16(afr[0], bB.v, (f16v)(0.0f), 0, 0, 0);
        f16v a1B = __builtin_amdgcn_mfma_f32_32x32x16_f16(afr[1], bB.v, (f16v)(0.0f), 0, 0, 0);

        float cA0 = 0.f, cA1 = 0.f, cA2 = 0.f, cA3 = 0.f;
        float cB0 = 0.f, cB1 = 0.f, cB2 = 0.f, cB3 = 0.f;
#pragma unroll
        for (int e = 0; e < 8; ++e) {      // |src| is a free VOP3 modifier
            cA0 = fmaf(fabsf(a0A[e]),     w2v[0][e],     cA0);
            cA1 = fmaf(fabsf(a0A[e + 8]), w2v[0][e + 8], cA1);
            cA2 = fmaf(fabsf(a1A[e]),     w2v[1][e],     cA2);
            cA3 = fmaf(fabsf(a1A[e + 8]), w2v[1][e + 8], cA3);
            cB0 = fmaf(fabsf(a0B[e]),     w2v[0][e],     cB0);
            cB1 = fmaf(fabsf(a0B[e + 8]), w2v[0][e + 8], cB1);
            cB2 = fmaf(fabsf(a1B[e]),     w2v[1][e],     cB2);
            cB3 = fmaf(fabsf(a1B[e + 8]), w2v[1][e + 8], cB3);
        }
        float psA = (cA0 + cA1) + (cA2 + cA3);
        float psB = (cB0 + cB1) + (cB2 + cB3);
        psA += __shfl_xor(psA, 32);        // abs part: combine the two K-halves
        psB += __shfl_xor(psB, 32);

        // linear part (exact matmul identity, separable)
        h2 ppA = __builtin_bit_cast(h2, pwA);
        h2 ppB = __builtin_bit_cast(h2, pwB);
        float linA = rowA + laneInv;
        linA = fmaf((float)ppA[0], Lp8r, linA);
        linA = fmaf((float)ppA[1], Lp9r, linA);
        float linB = rowB + laneInv;
        linB = fmaf((float)ppB[0], Lp8r, linB);
        linB = fmaf((float)ppB[1], Lp9r, linB);
        psA += linA;
        psB += linB;

        if (q == 0) {
            S[o][ilA][n] = psA;
            S[o][ilB][n] = psB;
        }
    }
    __syncthreads();

    // --- phase 3: symmetrized output + mirror (coalesced f4 stores) ---
    float b2 = b2v[0];
    {
        int il = t >> 3;
        int j0 = (t & 7) * 4;
        f4 a = *(const f4*)&S[0][il][j0];
        f4 b = *(const f4*)&S[1][il][j0];
        f4 v;
#pragma unroll
        for (int c = 0; c < 4; ++c) {
            float x = a[c] + b[c] + b2;
            if (bi == bj && il == j0 + c) x = -1e9f;
            v[c] = x;
        }
        *(f4*)&out[(size_t)(bi * 32 + il) * N + bj * 32 + j0] = v;

        if (bj > bi) {
            int jl = t >> 3;
            int i0 = (t & 7) * 4;
            f4 m;
#pragma unroll
            for (int c = 0; c < 4; ++c)
                m[c] = S[0][i0 + c][jl] + S[1][i0 + c][jl] + b2;
            *(f4*)&out[(size_t)(bj * 32 + jl) * N + bi * 32 + i0] = m;
        }
    }
}

extern "C" void kernel_launch(void* const* d_in, const int* in_sizes, int n_in,
                              void* d_out, int out_size, void* d_ws, size_t ws_size,
                              hipStream_t stream) {
    const float* z  = (const float*)d_in[0];  // [32]
    const float* s  = (const float*)d_in[1];  // [N]
    const float* W1 = (const float*)d_in[2];  // [42,64]
    const float* b1 = (const float*)d_in[3];  // [64]
    const float* W2 = (const float*)d_in[4];  // [64]
    const float* b2 = (const float*)d_in[5];  // [1]
    int N = in_sizes[1];                      // 2048

    float* out = (float*)d_out;
    int NB = N / 32;
    int nblk = NB * (NB + 1) / 2;             // 2080 for N=2048
    gd_mfma<<<nblk, 256, 0, stream>>>(z, s, W1, b1, W2, b2, out, N, NB);
}